// Round 13
// baseline (102.641 us; speedup 1.0000x reference)
//
#include <hip/hip_runtime.h>

// PhysicsGuidedAttention: B=2, N=2048, D=768, H=12, Hd=64
// qkv = x @ w_qkv.T ; flash-attn with elevation bias ; out = attn_out @ w_proj.T + b_proj
// R13: attn stages 128 kv rows per barrier (two independent 64-kv sub-steps
//      in one barrier span: QK0,QK1,SM0,PV0,SM1,PV1) -> barriers halved,
//      SM VALU hides under the other sub-step's MFMA, no accumulator doubling.
//      gemm1 = f32-A fused cvt + XCD remap; gemm2 64-row tiles; cvt2 weights.

typedef __attribute__((ext_vector_type(8))) short bf16x8;   // 8 bf16 = 4 VGPRs
typedef __attribute__((ext_vector_type(4))) float f32x4;
typedef __attribute__((ext_vector_type(16))) float f32x16;  // 32x32 accumulator

__device__ __forceinline__ unsigned short f2bf(float f) {
  unsigned int u = __builtin_bit_cast(unsigned int, f);
  u += 0x7fffu + ((u >> 16) & 1u);        // round-to-nearest-even
  return (unsigned short)(u >> 16);
}

__device__ __forceinline__ unsigned cvtpk(float lo, float hi) {
  unsigned r;
  asm("v_cvt_pk_bf16_f32 %0, %1, %2" : "=v"(r) : "v"(lo), "v"(hi));
  return r;
}

__device__ __forceinline__ float exp2v(float x) {
  float r;
  asm("v_exp_f32 %0, %1" : "=v"(r) : "v"(x));
  return r;
}

// XOR swizzle on element index: spreads 128B-stride row slots across banks.
// Depends only on row&63, so +64 subtile rows swizzle identically.
__device__ __forceinline__ int sw8(int row) {
  return ((row ^ (row >> 3)) & 7) << 3;
}

__device__ __forceinline__ void gload16(const unsigned short* g, unsigned short* l) {
  __builtin_amdgcn_global_load_lds(
      (const __attribute__((address_space(1))) unsigned int*)g,
      (__attribute__((address_space(3))) unsigned int*)l, 16, 0, 0);
}

// ---------------------------------------------------------------------------
// f32 -> bf16 converts for w_qkv and w_proj in one launch.
__global__ __launch_bounds__(256)
void cvt2_kernel(const float* __restrict__ a, unsigned short* __restrict__ ao, int na8,
                 const float* __restrict__ b, unsigned short* __restrict__ bo, int nb8) {
  int i = blockIdx.x * 256 + threadIdx.x;
  const float* src; unsigned short* dst;
  if (i < na8) { src = a; dst = ao; }
  else {
    i -= na8;
    if (i >= nb8) return;
    src = b; dst = bo;
  }
  const float4 f0 = ((const float4*)src)[i * 2];
  const float4 f1 = ((const float4*)src)[i * 2 + 1];
  uint4 v;
  v.x = cvtpk(f0.x, f0.y);
  v.y = cvtpk(f0.z, f0.w);
  v.z = cvtpk(f1.x, f1.y);
  v.w = cvtpk(f1.z, f1.w);
  ((uint4*)dst)[i] = v;
}

// ---------------------------------------------------------------------------
// gemm1: C[M,N] = A[M,K] @ B[N,K]^T with A = f32 (converted in staging regs),
// B bf16 via gload_lds, C bf16. 128x128 tile, BK=32, 2-phase dbuf (T14 for A).
__global__ __launch_bounds__(256)
void gemm_a32_kernel(const float* __restrict__ Ap,
                     const unsigned short* __restrict__ Bp,
                     unsigned short* __restrict__ Cp, int M, int N, int K) {
  __shared__ __align__(16) unsigned short lds_a[2][128 * 32];
  __shared__ __align__(16) unsigned short lds_b[2][128 * 32];
  const int t = threadIdx.x;
  const int l = t & 63;
  const int w = t >> 6;
  const int wr = w >> 1, wc = w & 1;
  const int bid = blockIdx.x + gridDim.x * blockIdx.y;   // linear dispatch order
  const int xcd = bid & 7;
  const int idx = bid >> 3;                              // 0..71
  const int brow = (xcd * 4 + (idx & 3)) * 128;
  const int bcol = (idx >> 2) * 128;
  const int l15 = l & 15, l4 = l >> 4;

  const int srow = t >> 2;
  const int scol = (t & 3) * 8;
  const float* ga = Ap + (size_t)(brow + srow) * K + scol;
  const unsigned short* gb = Bp + (size_t)(bcol + srow) * K + scol;

  f32x4 acc[4][4] = {};
  const int nk = K >> 5;

  float4 fa[4];
  {
    fa[0] = *(const float4*)ga;
    fa[1] = *(const float4*)(ga + 4);
    fa[2] = *(const float4*)(ga + (size_t)64 * K);
    fa[3] = *(const float4*)(ga + (size_t)64 * K + 4);
    unsigned short* lb = lds_b[0] + w * 512;
    gload16(gb, lb);
    gload16(gb + (size_t)64 * K, lb + 2048);
    uint4 u0, u1;
    u0.x = cvtpk(fa[0].x, fa[0].y); u0.y = cvtpk(fa[0].z, fa[0].w);
    u0.z = cvtpk(fa[1].x, fa[1].y); u0.w = cvtpk(fa[1].z, fa[1].w);
    u1.x = cvtpk(fa[2].x, fa[2].y); u1.y = cvtpk(fa[2].z, fa[2].w);
    u1.z = cvtpk(fa[3].x, fa[3].y); u1.w = cvtpk(fa[3].z, fa[3].w);
    *(uint4*)&lds_a[0][srow * 32 + scol] = u0;
    *(uint4*)&lds_a[0][(srow + 64) * 32 + scol] = u1;
  }
  __syncthreads();

  int buf = 0;
  for (int kt = 0; kt < nk; ++kt) {
    const bool more = kt + 1 < nk;
    if (more) {
      const size_t ko = (size_t)(kt + 1) * 32;
      fa[0] = *(const float4*)(ga + ko);
      fa[1] = *(const float4*)(ga + ko + 4);
      fa[2] = *(const float4*)(ga + ko + (size_t)64 * K);
      fa[3] = *(const float4*)(ga + ko + (size_t)64 * K + 4);
      unsigned short* lb = lds_b[buf ^ 1] + w * 512;
      gload16(gb + ko, lb);
      gload16(gb + ko + (size_t)64 * K, lb + 2048);
    }
    bf16x8 af[4], bfr[4];
#pragma unroll
    for (int i = 0; i < 4; ++i) {
      af[i]  = *(const bf16x8*)&lds_a[buf][(wr * 64 + i * 16 + l15) * 32 + l4 * 8];
      bfr[i] = *(const bf16x8*)&lds_b[buf][(wc * 64 + i * 16 + l15) * 32 + l4 * 8];
    }
#pragma unroll
    for (int i = 0; i < 4; ++i)
#pragma unroll
      for (int j = 0; j < 4; ++j)
        acc[i][j] = __builtin_amdgcn_mfma_f32_16x16x32_bf16(af[i], bfr[j], acc[i][j], 0, 0, 0);
    if (more) {
      uint4 u0, u1;
      u0.x = cvtpk(fa[0].x, fa[0].y); u0.y = cvtpk(fa[0].z, fa[0].w);
      u0.z = cvtpk(fa[1].x, fa[1].y); u0.w = cvtpk(fa[1].z, fa[1].w);
      u1.x = cvtpk(fa[2].x, fa[2].y); u1.y = cvtpk(fa[2].z, fa[2].w);
      u1.z = cvtpk(fa[3].x, fa[3].y); u1.w = cvtpk(fa[3].z, fa[3].w);
      *(uint4*)&lds_a[buf ^ 1][srow * 32 + scol] = u0;
      *(uint4*)&lds_a[buf ^ 1][(srow + 64) * 32 + scol] = u1;
    }
    __syncthreads();
    buf ^= 1;
  }

#pragma unroll
  for (int i = 0; i < 4; ++i)
#pragma unroll
    for (int j = 0; j < 4; ++j)
#pragma unroll
      for (int r = 0; r < 4; ++r) {
        const int row = brow + wr * 64 + i * 16 + l4 * 4 + r;
        const int col = bcol + wc * 64 + j * 16 + l15;
        Cp[(size_t)row * N + col] = f2bf(acc[i][j][r]);
      }
}

// ---------------------------------------------------------------------------
// gemm2: C[M,N] = A[M,K] @ B[N,K]^T + bias, all-bf16 inputs via gload_lds,
// C f32. 64x128 tile (384 blocks at M=4096,N=768), BK=32, 2-phase dbuf.
__global__ __launch_bounds__(256)
void gemm2_kernel(const unsigned short* __restrict__ Ap,
                  const unsigned short* __restrict__ Bp,
                  const float* __restrict__ bias, float* __restrict__ Cp,
                  int M, int N, int K) {
  __shared__ __align__(16) unsigned short lds_a[2][64 * 32];
  __shared__ __align__(16) unsigned short lds_b[2][128 * 32];
  const int t = threadIdx.x;
  const int l = t & 63;
  const int w = t >> 6;
  const int wr = w >> 1, wc = w & 1;
  const int brow = blockIdx.x * 64;
  const int bcol = blockIdx.y * 128;
  const int l15 = l & 15, l4 = l >> 4;

  const int srow = t >> 2;
  const int scol = (t & 3) * 8;
  const unsigned short* ga = Ap + (size_t)(brow + srow) * K + scol;
  const unsigned short* gb = Bp + (size_t)(bcol + srow) * K + scol;

  f32x4 acc[2][4] = {};
  const int nk = K >> 5;

  {
    gload16(ga, lds_a[0] + w * 512);
    unsigned short* lb = lds_b[0] + w * 512;
    gload16(gb, lb);
    gload16(gb + (size_t)64 * K, lb + 2048);
  }
  __syncthreads();

  int buf = 0;
  for (int kt = 0; kt < nk; ++kt) {
    if (kt + 1 < nk) {
      const size_t ko = (size_t)(kt + 1) * 32;
      gload16(ga + ko, lds_a[buf ^ 1] + w * 512);
      unsigned short* lb = lds_b[buf ^ 1] + w * 512;
      gload16(gb + ko, lb);
      gload16(gb + ko + (size_t)64 * K, lb + 2048);
    }
    bf16x8 af[2], bfr[4];
#pragma unroll
    for (int i = 0; i < 2; ++i)
      af[i] = *(const bf16x8*)&lds_a[buf][(wr * 32 + i * 16 + l15) * 32 + l4 * 8];
#pragma unroll
    for (int j = 0; j < 4; ++j)
      bfr[j] = *(const bf16x8*)&lds_b[buf][(wc * 64 + j * 16 + l15) * 32 + l4 * 8];
#pragma unroll
    for (int i = 0; i < 2; ++i)
#pragma unroll
      for (int j = 0; j < 4; ++j)
        acc[i][j] = __builtin_amdgcn_mfma_f32_16x16x32_bf16(af[i], bfr[j], acc[i][j], 0, 0, 0);
    __syncthreads();
    buf ^= 1;
  }

#pragma unroll
  for (int i = 0; i < 2; ++i)
#pragma unroll
    for (int j = 0; j < 4; ++j)
#pragma unroll
      for (int r = 0; r < 4; ++r) {
        const int row = brow + wr * 32 + i * 16 + l4 * 4 + r;
        const int col = bcol + wc * 64 + j * 16 + l15;
        Cp[(size_t)row * N + col] = acc[i][j][r] + bias[col];
      }
}

// ---------------------------------------------------------------------------
// Flash attention, 32x32x16 MFMA, swapped QK^T, no max-tracking, ones-MFMA psum.
// grid = (B*H, N/256); 512 thr = 8 waves; wave w owns q [q0+32w, q0+32w+32).
// 128 kv rows staged per barrier span; two independent 64-kv sub-steps
// (QK0,QK1,SM0,PV0,SM1,PV1) share the o/ps accumulators.
__global__ __launch_bounds__(512)
void attn_kernel(const unsigned short* __restrict__ qkv,
                 const float* __restrict__ elev,
                 const float* __restrict__ alpha_p,
                 unsigned short* __restrict__ aout) {
  __shared__ __align__(16) unsigned short lds_k[2][128 * 64];   // [buf][kv][d] swz
  __shared__ __align__(16) unsigned short lds_vt[2][64 * 128];  // [buf][d][kv] swz
  __shared__ __align__(16) float lds_ej[2][128];

  const int t = threadIdx.x;
  const int l = t & 63;
  const int w = t >> 6;                    // 0..7
  const int l31 = l & 31;
  const int h = l >> 5;
  const int b = blockIdx.x / 12, hd = blockIdx.x % 12;
  const int q0 = blockIdx.y * 256 + w * 32;

  const float cE = fmaxf(alpha_p[0], 0.f) * (1.4426950408889634f * 1e-3f);
  const float c1 = 0.18033688011112042f;   // 0.125 * log2(e)

  const size_t rs = 2304;
  const unsigned short* qbase = qkv + ((size_t)b * 2048) * rs + hd * 64;
  const unsigned short* kbase = qbase + 768;
  const unsigned short* vbase = qbase + 1536;

  bf16x8 qa[4];
  {
    const unsigned short* qp = qbase + (size_t)(q0 + l31) * rs + h * 8;
#pragma unroll
    for (int ks = 0; ks < 4; ++ks) qa[ks] = *(const bf16x8*)(qp + ks * 16);
  }
  const float eiv = elev[(size_t)b * 2048 + q0 + l31] * cE;

  uint4 onesu; onesu.x = onesu.y = onesu.z = onesu.w = 0x3F803F80u;
  const bf16x8 onesf = __builtin_bit_cast(bf16x8, onesu);

  f32x16 o[2] = {};
  f32x16 ps = {};

  // staging: thread t covers kv rows sr and sr+64, d cols sc..sc+8
  const int sr = t >> 3;          // 0..63
  const int sc = (t & 7) * 8;

  uint4 rk[2], rv[2];
  float evn = 0.f;

  // ---- prologue: stage kv rows 0..127 into buf 0 ----
  rk[0] = *(const uint4*)(kbase + (size_t)sr * rs + sc);
  rk[1] = *(const uint4*)(kbase + (size_t)(sr + 64) * rs + sc);
  rv[0] = *(const uint4*)(vbase + (size_t)sr * rs + sc);
  rv[1] = *(const uint4*)(vbase + (size_t)(sr + 64) * rs + sc);
  if (t < 128) evn = elev[(size_t)b * 2048 + t];
#pragma unroll
  for (int i = 0; i < 2; ++i) {
    const int r = sr + i * 64;
    *(uint4*)&lds_k[0][r * 64 + (sc ^ sw8(r))] = rk[i];
    union { uint4 u; unsigned short s2[8]; } vu; vu.u = rv[i];
#pragma unroll
    for (int j = 0; j < 8; ++j) {
      const int d = sc + j;
      lds_vt[0][d * 128 + (r ^ sw8(d))] = vu.s2[j];
    }
  }
  if (t < 128) lds_ej[0][t] = evn * cE;
  __syncthreads();

  for (int s = 0; s < 16; ++s) {
    const int cur = s & 1;
    const bool more = s < 15;
    if (more) {                            // prefetch next 128 kv into regs
      const int kvn = (s + 1) * 128;
      rk[0] = *(const uint4*)(kbase + (size_t)(kvn + sr) * rs + sc);
      rk[1] = *(const uint4*)(kbase + (size_t)(kvn + sr + 64) * rs + sc);
      rv[0] = *(const uint4*)(vbase + (size_t)(kvn + sr) * rs + sc);
      rv[1] = *(const uint4*)(vbase + (size_t)(kvn + sr + 64) * rs + sc);
      if (t < 128) evn = elev[(size_t)b * 2048 + kvn + t];
    }

    // --- QK for both sub-tiles (st0, st1 independent) ---
    f32x16 st0[2] = {}, st1[2] = {};
    __builtin_amdgcn_s_setprio(1);
#pragma unroll
    for (int kst = 0; kst < 4; ++kst) {
      const int col = kst * 16 + h * 8;
#pragma unroll
      for (int mb = 0; mb < 2; ++mb) {
        const int row = mb * 32 + l31;
        bf16x8 kf = *(const bf16x8*)&lds_k[cur][row * 64 + (col ^ sw8(row))];
        st0[mb] = __builtin_amdgcn_mfma_f32_32x32x16_bf16(kf, qa[kst], st0[mb], 0, 0, 0);
      }
    }
#pragma unroll
    for (int kst = 0; kst < 4; ++kst) {
      const int col = kst * 16 + h * 8;
#pragma unroll
      for (int mb = 0; mb < 2; ++mb) {
        const int row = 64 + mb * 32 + l31;
        bf16x8 kf = *(const bf16x8*)&lds_k[cur][row * 64 + (col ^ sw8(row))];
        st1[mb] = __builtin_amdgcn_mfma_f32_32x32x16_bf16(kf, qa[kst], st1[mb], 0, 0, 0);
      }
    }
    __builtin_amdgcn_s_setprio(0);

    // --- SM0 -> pa0 (VALU; can overlap QK1/PV tails) ---
    bf16x8 pa0[4], pa1[4];
#pragma unroll
    for (int mb = 0; mb < 2; ++mb) {
      float p16[16];
#pragma unroll
      for (int rr = 0; rr < 4; ++rr) {
        const float4 ejq = *(const float4*)&lds_ej[cur][mb * 32 + rr * 8 + h * 4];
#pragma unroll
        for (int jl = 0; jl < 4; ++jl) {
          const int r = rr * 4 + jl;
          const float bm = __builtin_amdgcn_fmed3f(ejq[jl] - eiv, 0.f, 14.4269504f);
          p16[r] = exp2v(__builtin_fmaf(st0[mb][r], c1, -bm));
        }
      }
#pragma unroll
      for (int ks2 = 0; ks2 < 2; ++ks2) {
        unsigned u0 = cvtpk(p16[ks2 * 8 + 0], p16[ks2 * 8 + 1]);
        unsigned u1 = cvtpk(p16[ks2 * 8 + 2], p16[ks2 * 8 + 3]);
        unsigned v0 = cvtpk(p16[ks2 * 8 + 4], p16[ks2 * 8 + 5]);
        unsigned v1 = cvtpk(p16[ks2 * 8 + 6], p16[ks2 * 8 + 7]);
        asm volatile("v_permlane32_swap_b32 %0, %1" : "+v"(u0), "+v"(v0));
        asm volatile("v_permlane32_swap_b32 %0, %1" : "+v"(u1), "+v"(v1));
        uint4 fr; fr.x = u0; fr.y = u1; fr.z = v0; fr.w = v1;
        pa0[mb * 2 + ks2] = __builtin_bit_cast(bf16x8, fr);
      }
    }

    // --- PV0 ---
    __builtin_amdgcn_s_setprio(1);
#pragma unroll
    for (int ks = 0; ks < 4; ++ks) {
      const int colb = ks * 16 + h * 8;
#pragma unroll
      for (int nb = 0; nb < 2; ++nb) {
        const int row = nb * 32 + l31;
        bf16x8 vf = *(const bf16x8*)&lds_vt[cur][row * 128 + (colb ^ sw8(row))];
        o[nb] = __builtin_amdgcn_mfma_f32_32x32x16_bf16(pa0[ks], vf, o[nb], 0, 0, 0);
      }
      ps = __builtin_amdgcn_mfma_f32_32x32x16_bf16(pa0[ks], onesf, ps, 0, 0, 0);
    }
    __builtin_amdgcn_s_setprio(0);

    // --- SM1 -> pa1 (overlaps PV0 tail) ---
#pragma unroll
    for (int mb = 0; mb < 2; ++mb) {
      float p16[16];
#pragma unroll
      for (int rr = 0; rr < 4; ++rr) {
        const float4 ejq = *(const float4*)&lds_ej[cur][64 + mb * 32 + rr * 8 + h * 4];
#pragma unroll
        for (int jl = 0; jl < 4; ++jl) {
          const int r = rr * 4 + jl;
          const float bm = __builtin_amdgcn_fmed3f(ejq[jl] - eiv, 0.f, 14.4269504f);
          p16[r] = exp2v(__builtin_fmaf(st1[mb][r], c1, -bm));
        }
      }
#pragma unroll
      for (int ks2 = 0; ks2 < 2; ++ks2) {
        unsigned u0 = cvtpk(p16[ks2 * 8 + 0], p16[ks2 * 8 + 1]);
        unsigned u1 = cvtpk(p16[ks2 * 8 + 2], p16[ks2 * 8 + 3]);
        unsigned v0 = cvtpk(p16[ks2 * 8 + 4], p16[ks2 * 8 + 5]);
        unsigned v1 = cvtpk(p16[ks2 * 8 + 6], p16[ks2 * 8 + 7]);
        asm volatile("v_permlane32_swap_b32 %0, %1" : "+v"(u0), "+v"(v0));
        asm volatile("v_permlane32_swap_b32 %0, %1" : "+v"(u1), "+v"(v1));
        uint4 fr; fr.x = u0; fr.y = u1; fr.z = v0; fr.w = v1;
        pa1[mb * 2 + ks2] = __builtin_bit_cast(bf16x8, fr);
      }
    }

    // --- PV1 ---
    __builtin_amdgcn_s_setprio(1);
#pragma unroll
    for (int ks = 0; ks < 4; ++ks) {
      const int colb = 64 + ks * 16 + h * 8;
#pragma unroll
      for (int nb = 0; nb < 2; ++nb) {
        const int row = nb * 32 + l31;
        bf16x8 vf = *(const bf16x8*)&lds_vt[cur][row * 128 + (colb ^ sw8(row))];
        o[nb] = __builtin_amdgcn_mfma_f32_32x32x16_bf16(pa1[ks], vf, o[nb], 0, 0, 0);
      }
      ps = __builtin_amdgcn_mfma_f32_32x32x16_bf16(pa1[ks], onesf, ps, 0, 0, 0);
    }
    __builtin_amdgcn_s_setprio(0);

    // --- T14 late-write next 128 kv ---
    if (more) {
      const int nxt = cur ^ 1;
#pragma unroll
      for (int i = 0; i < 2; ++i) {
        const int r = sr + i * 64;
        *(uint4*)&lds_k[nxt][r * 64 + (sc ^ sw8(r))] = rk[i];
        union { uint4 u; unsigned short s2[8]; } vu; vu.u = rv[i];
#pragma unroll
        for (int j = 0; j < 8; ++j) {
          const int d = sc + j;
          lds_vt[nxt][d * 128 + (r ^ sw8(d))] = vu.s2[j];
        }
      }
      if (t < 128) lds_ej[nxt][t] = evn * cE;
    }
    __syncthreads();
  }

  // --- epilogue: purely per-lane normalize (ps rows == o rows), store bf16 ---
  float inv[16];
#pragma unroll
  for (int r = 0; r < 16; ++r) inv[r] = 1.0f / ps[r];
#pragma unroll
  for (int nb = 0; nb < 2; ++nb) {
    const int col = hd * 64 + nb * 32 + l31;
#pragma unroll
    for (int rr = 0; rr < 4; ++rr)
#pragma unroll
      for (int jl = 0; jl < 4; ++jl) {
        const int r = rr * 4 + jl;
        const int q = q0 + rr * 8 + h * 4 + jl;
        aout[((size_t)b * 2048 + q) * 768 + col] = f2bf(o[nb][r] * inv[r]);
      }
  }
}

extern "C" void kernel_launch(void* const* d_in, const int* in_sizes, int n_in,
                              void* d_out, int out_size, void* d_ws, size_t ws_size,
                              hipStream_t stream) {
  const float* x      = (const float*)d_in[0];   // [2,2048,768]
  const float* elev   = (const float*)d_in[1];   // [2,2048]
  const float* w_qkv  = (const float*)d_in[2];   // [2304,768]
  const float* w_proj = (const float*)d_in[3];   // [768,768]
  const float* b_proj = (const float*)d_in[4];   // [768]
  const float* alpha  = (const float*)d_in[5];   // [1]
  float* out = (float*)d_out;                    // [2,2048,768] f32

  // ws layout (bf16): qkvb [4096,2304] ; aob [4096,768] ; wqkvb [2304,768] ;
  // wprojb [768,768]  => 29.9 MB total
  unsigned short* qkvb   = (unsigned short*)d_ws;
  unsigned short* aob    = qkvb + (size_t)4096 * 2304;
  unsigned short* wqkvb  = aob + (size_t)4096 * 768;
  unsigned short* wprojb = wqkvb + (size_t)2304 * 768;

  cvt2_kernel<<<1152, 256, 0, stream>>>(w_qkv, wqkvb, 2304 * 768 / 8,
                                        w_proj, wprojb, 768 * 768 / 8);

  gemm_a32_kernel<<<dim3(32, 18), 256, 0, stream>>>(
      x, wqkvb, qkvb, 4096, 2304, 768);

  attn_kernel<<<dim3(24, 8), 512, 0, stream>>>(qkvb, elev, alpha, aob);

  gemm2_kernel<<<dim3(64, 6), 256, 0, stream>>>(
      aob, wprojb, b_proj, out, 4096, 768, 768);
}